// Round 10
// baseline (3804.972 us; speedup 1.0000x reference)
//
#include <hip/hip_runtime.h>

#define TT 2048
#define BB 8
#define DD 1024
#define HH 1024
#define CHB 128   // channels per block

typedef unsigned int u32;
typedef unsigned short u16;
typedef unsigned long long u64;
typedef float f32x4 __attribute__((ext_vector_type(4)));
typedef u32 u32x2 __attribute__((ext_vector_type(2)));
typedef _Float16 f16x8 __attribute__((ext_vector_type(8)));

static __device__ __forceinline__ u16 f16bits(float x) {
    _Float16 h = (_Float16)x;
    u16 r;
    __builtin_memcpy(&r, &h, 2);
    return r;
}

// fast tanh: tanh(x) = sign(x) * (1 - e^{-2|x|}) / (1 + e^{-2|x|}), exp2-based
static __device__ __forceinline__ float fast_tanh(float x) {
    const float ax = __builtin_fabsf(x);
    const float e = __builtin_amdgcn_exp2f(ax * -2.885390082f);
    const float r = (1.0f - e) * __builtin_amdgcn_rcpf(1.0f + e);
    return __builtin_copysignf(r, x);
}

// ---------------- tag invalidation (every launch: no cross-call state) ----------------
__global__ __launch_bounds__(256) void clear_hb_kernel(u32* hb) {
    const int i = blockIdx.x * 256 + threadIdx.x;   // 64 x 256 = 16384 granules
    __hip_atomic_store(&hb[i], 0xFFFF0000u, __ATOMIC_RELAXED, __HIP_MEMORY_SCOPE_AGENT);
}

// ---------------- fused projection GEMMs via MFMA fp16 ----------------
__global__ __launch_bounds__(256) void proj_kernel(
    const float* __restrict__ x, const float* __restrict__ Wx,
    const float* __restrict__ Wd, const float* __restrict__ bias,
    const float* __restrict__ bdel, float* __restrict__ xw_out,
    float* __restrict__ decay_out)
{
    __shared__ __align__(16) _Float16 xs[64][40];
    __shared__ __align__(16) _Float16 wxs[64][40];
    __shared__ __align__(16) _Float16 wds[64][40];

    const int tid = threadIdx.x;
    const int bm = blockIdx.y * 64;
    const int bn = blockIdx.x * 64;
    const int w = tid >> 6, l = tid & 63;
    const int ar = l & 15, kg = l >> 4;
    const int srow = tid >> 2, scol = (tid & 3) * 8;

    f32x4 accx[4], accd[4];
#pragma unroll
    for (int ct = 0; ct < 4; ++ct) {
        accx[ct] = (f32x4){0.f, 0.f, 0.f, 0.f};
        accd[ct] = (f32x4){0.f, 0.f, 0.f, 0.f};
    }

    for (int k0 = 0; k0 < DD; k0 += 32) {
        const float* xp = &x[(size_t)(bm + srow) * DD + k0 + scol];
        const float* wxp = &Wx[(size_t)(bn + srow) * DD + k0 + scol];
        const float* wdp = &Wd[(size_t)(bn + srow) * DD + k0 + scol];
        f32x4 a0 = *(const f32x4*)xp,  a1 = *(const f32x4*)(xp + 4);
        f32x4 b0 = *(const f32x4*)wxp, b1 = *(const f32x4*)(wxp + 4);
        f32x4 c0 = *(const f32x4*)wdp, c1 = *(const f32x4*)(wdp + 4);
        f16x8 ha, hb_, hc;
#pragma unroll
        for (int e = 0; e < 4; ++e) {
            ha[e] = (_Float16)a0[e];  ha[e + 4] = (_Float16)a1[e];
            hb_[e] = (_Float16)b0[e]; hb_[e + 4] = (_Float16)b1[e];
            hc[e] = (_Float16)c0[e];  hc[e + 4] = (_Float16)c1[e];
        }
        __syncthreads();
        *(f16x8*)&xs[srow][scol] = ha;
        *(f16x8*)&wxs[srow][scol] = hb_;
        *(f16x8*)&wds[srow][scol] = hc;
        __syncthreads();

        const f16x8 af = *(const f16x8*)&xs[w * 16 + ar][kg * 8];
#pragma unroll
        for (int ct = 0; ct < 4; ++ct) {
            const f16x8 bfx = *(const f16x8*)&wxs[ct * 16 + ar][kg * 8];
            const f16x8 bfd = *(const f16x8*)&wds[ct * 16 + ar][kg * 8];
            accx[ct] = __builtin_amdgcn_mfma_f32_16x16x32_f16(af, bfx, accx[ct], 0, 0, 0);
            accd[ct] = __builtin_amdgcn_mfma_f32_16x16x32_f16(af, bfd, accd[ct], 0, 0, 0);
        }
    }

#pragma unroll
    for (int ct = 0; ct < 4; ++ct) {
        const int col = bn + ct * 16 + ar;
        const float bx = bias[col];
        const float bd = bdel[col];
#pragma unroll
        for (int j = 0; j < 4; ++j) {
            const int row = bm + w * 16 + kg * 4 + j;
            xw_out[(size_t)row * HH + col] = accx[ct][j] + bx;
            decay_out[(size_t)row * HH + col] = 1.0f / (1.0f + expf(accd[ct][j] + bd));
        }
    }
}

// ---------------- sequential scan: B-frag sharing across 8 channel-tiles ----------------
// 64 blocks x 512 threads (8 waves). Block (b=blk&7, g=blk>>3) owns channels
// [g*128,+128) of batch b. Shared strip hst[2][1024] (tag-in-data poll, R8).
// NEW vs R8: wave w owns K-slice [w*128,+128) x ALL 128 channels as 8 A-tiles
// in registers. Each of the 4 B-frags per step is read from LDS ONCE and
// reused by 8 MFMAs -> LDS B-traffic 256KB -> 32KB per block-step (the R8
// hidden bottleneck: 256 ds_read_b128 = ~2000 cyc >= half the step). Cost:
// K-partials summed across waves via red[8][128] + a second barrier.
// red needs no ping-pong: partial-writes(t+1) come after barrier1(t+1), which
// epilogue threads reach only after their red-reads(t).
__global__ __launch_bounds__(512) void scan_kernel(
    const float* __restrict__ h0, const float* __restrict__ R,
    const float* __restrict__ decay, float* __restrict__ out,
    u32* __restrict__ hb)
{
    __shared__ __align__(16) _Float16 hst[2][HH];   // ping-pong strip, 4 KB
    __shared__ __align__(16) float red[8][136];     // per-wave K-partials, 4.25 KB

    const int tid = threadIdx.x;
    const int w = tid >> 6;
    const int l = tid & 63;
    const int ar = l & 15, kg = l >> 4;
    const int b = blockIdx.x & 7, g = blockIdx.x >> 3;

    // ---- one-time A fragments: 8 ch-tiles x 4 k-chunks of this wave's K-slice ----
    // afrag[c][s]: channel g*128 + c*16 + ar, k = w*128 + s*32 + kg*8 .. +8
    f16x8 afrag[8][4];
#pragma unroll
    for (int c = 0; c < 8; ++c)
#pragma unroll
        for (int s = 0; s < 4; ++s) {
            const float* rp = &R[(size_t)(g * CHB + c * 16 + ar) * HH
                                 + w * 128 + s * 32 + kg * 8];
            const f32x4 r0 = *(const f32x4*)rp;
            const f32x4 r1 = *(const f32x4*)(rp + 4);
            f16x8 a;
#pragma unroll
            for (int e = 0; e < 4; ++e) { a[e] = (_Float16)r0[e]; a[e + 4] = (_Float16)r1[e]; }
            afrag[c][s] = a;
        }

    const bool pollme = ((tid >> 6) != g);

    // epilogue lanes: tid<128 handle channel g*128 + tid
    const bool ep = (tid < CHB);
    float hp = 0.f, xw_c = 0.f, d_c = 0.f;
    if (ep) {
        hp = h0[(size_t)b * HH + g * CHB + tid];
        xw_c = out[(size_t)b * HH + g * CHB + tid];   // row 0 projection (intact)
        d_c = decay[(size_t)b * HH + g * CHB + tid];
    }

    for (int t = 0; t < TT; ++t) {
        const int p = t & 1;
        // ---- fill strip p: staggered double-poll of remote granules (R8) ----
        if (t == 0) {
            const float2 v = *(const float2*)&h0[(size_t)b * HH + tid * 2];
            *(u32*)&hst[0][tid * 2] = (u32)f16bits(v.x) | ((u32)f16bits(v.y) << 16);
        } else if (pollme) {
            const u32 expt = (u32)(t - 1) << 16;
            const u64 gp = (u64)hb
                         + (u64)(((t - 1) & 1) * (BB * HH) + b * HH + tid * 2) * 4;
            u32x2 gA, gB, gr;
            asm volatile("global_load_dwordx2 %0, %1, off sc0 sc1"
                         : "=v"(gA) : "v"(gp));
            __builtin_amdgcn_s_sleep(4);
            asm volatile("global_load_dwordx2 %0, %1, off sc0 sc1"
                         : "=v"(gB) : "v"(gp));
            while (true) {
                asm volatile("s_waitcnt vmcnt(1)" ::: "memory");   // slot A landed
                __builtin_amdgcn_sched_barrier(0);
                if (!(((gA[0] ^ expt) | (gA[1] ^ expt)) & 0xffff0000u)) { gr = gA; break; }
                asm volatile("global_load_dwordx2 %0, %1, off sc0 sc1"
                             : "=v"(gA) : "v"(gp));
                asm volatile("s_waitcnt vmcnt(1)" ::: "memory");   // slot B landed
                __builtin_amdgcn_sched_barrier(0);
                if (!(((gB[0] ^ expt) | (gB[1] ^ expt)) & 0xffff0000u)) { gr = gB; break; }
                asm volatile("global_load_dwordx2 %0, %1, off sc0 sc1"
                             : "=v"(gB) : "v"(gp));
            }
            asm volatile("s_waitcnt vmcnt(0)" ::: "memory");   // drain outstanding slot
            __builtin_amdgcn_sched_barrier(0);
            *(u32*)&hst[p][tid * 2] = (gr[0] & 0xffffu) | (gr[1] << 16);
        }
        __syncthreads();   // barrier 1: strip p complete

        // ---- prefetch NEXT step's xw/decay (hides under this step) ----
        float xw_n = xw_c, d_n = d_c;
        if (ep && t + 1 < TT) {
            const size_t nidx = (size_t)(t + 1) * (BB * HH) + (size_t)b * HH + g * CHB + tid;
            xw_n = out[nidx];
            d_n = decay[nidx];
        }

        // ---- 4 shared B-frags x 8 channel-tiles = 32 MFMAs, K-partials ----
        f16x8 bf[4];
#pragma unroll
        for (int s = 0; s < 4; ++s)
            bf[s] = *(const f16x8*)&hst[p][w * 128 + s * 32 + kg * 8];
        f32x4 acc[8];
#pragma unroll
        for (int c = 0; c < 8; ++c) acc[c] = (f32x4){0.f, 0.f, 0.f, 0.f};
#pragma unroll
        for (int s = 0; s < 4; ++s)
#pragma unroll
            for (int c = 0; c < 8; ++c)
                acc[c] = __builtin_amdgcn_mfma_f32_16x16x32_f16(
                             afrag[c][s], bf[s], acc[c], 0, 0, 0);

        // ---- partial write: C col0 lanes (l&15==0); rows kg*4+j of tile c ----
        if (ar == 0) {
#pragma unroll
            for (int c = 0; c < 8; ++c)
                *(f32x4*)&red[w][c * 16 + kg * 4] = acc[c];
        }
        __syncthreads();   // barrier 2: partials complete

        // ---- epilogue: 128 lanes sum 8 K-partials; pointwise; broadcast ----
        if (ep) {
            float s = red[0][tid] + red[1][tid] + red[2][tid] + red[3][tid]
                    + red[4][tid] + red[5][tid] + red[6][tid] + red[7][tid];
            const float cand = fast_tanh(s + xw_c);
            const float hnew = d_c * hp + (1.0f - d_c) * cand;
            hp = hnew;
            const u16 hbits = f16bits(hnew);
            const u32 gran = ((u32)t << 16) | (u32)hbits;
            const u64 dst = (u64)hb
                          + (u64)((t & 1) * (BB * HH) + b * HH + g * CHB + tid) * 4;
            asm volatile("global_store_dword %0, %1, off sc0 sc1"
                         :: "v"(dst), "v"(gran) : "memory");
            hst[p ^ 1][g * CHB + tid] = *(const _Float16*)&hbits;  // own-range shortcut
            out[(size_t)t * (BB * HH) + (size_t)b * HH + g * CHB + tid] = hnew;
        }
        xw_c = xw_n;
        d_c = d_n;
    }
}

// ---------------- launch ----------------
extern "C" void kernel_launch(void* const* d_in, const int* in_sizes, int n_in,
                              void* d_out, int out_size, void* d_ws, size_t ws_size,
                              hipStream_t stream) {
    const float* x    = (const float*)d_in[0];
    const float* h0   = (const float*)d_in[1];
    const float* Wx   = (const float*)d_in[2];
    const float* R    = (const float*)d_in[3];
    const float* bias = (const float*)d_in[4];
    const float* Wd   = (const float*)d_in[5];
    const float* bdel = (const float*)d_in[6];
    float* out = (float*)d_out;

    float* decay = (float*)d_ws;                                 // 64 MiB
    u32* hb = (u32*)((char*)d_ws + (size_t)TT * BB * HH * 4);    // 2 x 32 KiB ping-pong

    clear_hb_kernel<<<64, 256, 0, stream>>>(hb);
    proj_kernel<<<dim3(HH / 64, (TT * BB) / 64), 256, 0, stream>>>(
        x, Wx, Wd, bias, bdel, out, decay);
    scan_kernel<<<64, 512, 0, stream>>>(h0, R, decay, out, hb);
}